// Round 4
// baseline (430630.127 us; speedup 1.0000x reference)
//
#include <hip/hip_runtime.h>
#include <math.h>

#define NS 512          // states
#define NI 32           // inputs
#define NO 16           // outputs
#define TT 4096         // time points
#define NSTEP (TT - 1)  // 4095 integration steps
#define TPB 1024        // one workgroup: 16 waves on ONE CU

// Single-workgroup integrator: all cross-row exchange via LDS double buffer +
// __syncthreads (~100 cy) instead of agent-scope LLC round trips (~7800 cy).
// A (512x512 fp32 = 1 MB) lives in registers: 256 VGPR/lane across 1024 lanes.
// x distributed over 32-lane half-waves (16 floats/lane); each half-wave
// computes 16 full row-dots and pack-butterfly-reduces in 4 levels + 1 add.

__global__ __launch_bounds__(TPB, 1)
void flow_main(const float* __restrict__ x0,
               const float* __restrict__ tt,
               const float* __restrict__ uc,   // (4, 4095, 32): d,c,b,a
               const float* __restrict__ A,    // (512, 512)
               const float* __restrict__ B,    // (512, 32)
               float* __restrict__ xs)         // (4096, 512)
{
    __shared__ float xb[2][NS];   // double-buffered state vector (4 KB)

    const int tid = threadIdx.x;
    const int l   = tid & 63;          // lane
    const int w   = tid >> 6;          // wave 0..15
    const int h   = (l >> 5) & 1;      // half-wave
    const int q   = l & 31;            // x-distribution index within half
    // pack-butterfly row mapping: row bit k <- lane bit (4-k)
    const int rloc = ((l >> 4) & 1) | (((l >> 3) & 1) << 1)
                   | (((l >> 2) & 1) << 2) | (((l >> 1) & 1) << 3);
    const int rbase = w * 32 + h * 16;
    const int r     = rbase + rloc;    // my row (lane pair l^1 shares it)

    const float dt = tt[1] - tt[0];

    // A tile in registers: a[i][j] = A[rbase+i][j*32+q]
    float a[16][16];
#pragma unroll
    for (int i = 0; i < 16; ++i)
#pragma unroll
        for (int j = 0; j < 16; ++j)
            a[i][j] = A[(rbase + i) * NS + j * 32 + q];

    // my row of B in registers
    float brow[NI];
    {
        const float4* Bp = (const float4*)(B + r * NI);
#pragma unroll
        for (int c = 0; c < 8; ++c) {
            const float4 v = Bp[c];
            brow[4 * c + 0] = v.x; brow[4 * c + 1] = v.y;
            brow[4 * c + 2] = v.z; brow[4 * c + 3] = v.w;
        }
    }

    float x = x0[r];                   // my row's state
    float xv[16];                      // stage input vector, my 16 columns
#pragma unroll
    for (int j = 0; j < 16; ++j) xv[j] = x0[j * 32 + q];
    if ((l & 1) == 0) xs[r] = x;       // xs[0] = x0

    const float SOFF[6] = {0.0f, 0.2f * dt, 0.3f * dt, 0.8f * dt,
                           (8.0f / 9.0f) * dt, dt};
    float k[6];

    for (int n = 0; n < NSTEP; ++n) {
        // Bu cubic coefficients for my row: pq = dot(B[r,:], ucq[n,:])
        const float* un = uc + n * NI;
        float pd = 0.0f, pc = 0.0f, pb = 0.0f, pa = 0.0f;
#pragma unroll
        for (int c = 0; c < 8; ++c) {
            const float4 vd = ((const float4*)(un + 0 * NSTEP * NI))[c];
            const float4 vc = ((const float4*)(un + 1 * NSTEP * NI))[c];
            const float4 vb = ((const float4*)(un + 2 * NSTEP * NI))[c];
            const float4 va = ((const float4*)(un + 3 * NSTEP * NI))[c];
            pd += brow[4*c]*vd.x + brow[4*c+1]*vd.y + brow[4*c+2]*vd.z + brow[4*c+3]*vd.w;
            pc += brow[4*c]*vc.x + brow[4*c+1]*vc.y + brow[4*c+2]*vc.z + brow[4*c+3]*vc.w;
            pb += brow[4*c]*vb.x + brow[4*c+1]*vb.y + brow[4*c+2]*vb.z + brow[4*c+3]*vb.w;
            pa += brow[4*c]*va.x + brow[4*c+1]*va.y + brow[4*c+2]*va.z + brow[4*c+3]*va.w;
        }

#pragma unroll
        for (int s = 0; s < 6; ++s) {
            // gs = 6n+s -> gs&1 == s&1 (compile-time buffer parity)
            if (!(n == 0 && s == 0)) {
#pragma unroll
                for (int j = 0; j < 16; ++j)
                    xv[j] = xb[s & 1][j * 32 + q];
            }

            const float sv = SOFF[s];
            const float bu = pa + sv * (pb + sv * (pc + sv * pd));

            // 16 row-partials over my 16 columns
            float sc[16];
#pragma unroll
            for (int i = 0; i < 16; ++i) {
                float t0 = 0.0f;
#pragma unroll
                for (int j = 0; j < 16; ++j) t0 += a[i][j] * xv[j];
                sc[i] = t0;
            }
            // pack-butterfly within 32-lane half: 4 levels + final add
            float t8[8];
#pragma unroll
            for (int i = 0; i < 8; ++i) {
                const float send = (l & 16) ? sc[2*i] : sc[2*i+1];
                const float keep = (l & 16) ? sc[2*i+1] : sc[2*i];
                t8[i] = keep + __shfl_xor(send, 16, 64);
            }
            float t4[4];
#pragma unroll
            for (int i = 0; i < 4; ++i) {
                const float send = (l & 8) ? t8[2*i] : t8[2*i+1];
                const float keep = (l & 8) ? t8[2*i+1] : t8[2*i];
                t4[i] = keep + __shfl_xor(send, 8, 64);
            }
            float t2[2];
#pragma unroll
            for (int i = 0; i < 2; ++i) {
                const float send = (l & 4) ? t4[2*i] : t4[2*i+1];
                const float keep = (l & 4) ? t4[2*i+1] : t4[2*i];
                t2[i] = keep + __shfl_xor(send, 4, 64);
            }
            float t1;
            {
                const float send = (l & 2) ? t2[0] : t2[1];
                const float keep = (l & 2) ? t2[1] : t2[0];
                t1 = keep + __shfl_xor(send, 2, 64);
                t1 += __shfl_xor(t1, 1, 64);
            }
            // fast tanh: 1 - 2/(e^{2x}+1)  (v_exp + v_rcp, ~1e-7 abs err)
            const float e  = __expf(2.0f * t1);
            k[s] = (1.0f - 2.0f / (e + 1.0f)) + bu;

            float nxt;
            if (s == 0) {
                nxt = x + dt * (0.2f * k[0]);
            } else if (s == 1) {
                nxt = x + dt * ((3.0f / 40.0f) * k[0] + (9.0f / 40.0f) * k[1]);
            } else if (s == 2) {
                nxt = x + dt * ((44.0f / 45.0f) * k[0] + (-56.0f / 15.0f) * k[1] +
                                (32.0f / 9.0f) * k[2]);
            } else if (s == 3) {
                nxt = x + dt * ((19372.0f / 6561.0f) * k[0] + (-25360.0f / 2187.0f) * k[1] +
                                (64448.0f / 6561.0f) * k[2] + (-212.0f / 729.0f) * k[3]);
            } else if (s == 4) {
                nxt = x + dt * ((9017.0f / 3168.0f) * k[0] + (-355.0f / 33.0f) * k[1] +
                                (46732.0f / 5247.0f) * k[2] + (49.0f / 176.0f) * k[3] +
                                (-5103.0f / 18656.0f) * k[4]);
            } else {
                nxt = x + dt * ((35.0f / 384.0f) * k[0] + (500.0f / 1113.0f) * k[2] +
                                (125.0f / 192.0f) * k[3] + (-2187.0f / 6784.0f) * k[4] +
                                (11.0f / 84.0f) * k[5]);
                x = nxt;
                if ((l & 1) == 0) xs[(n + 1) * NS + r] = nxt;
            }

            if ((l & 1) == 0) xb[(s + 1) & 1][r] = nxt;
            __syncthreads();
        }
    }
}

__global__ __launch_bounds__(256, 1)
void flow_ys(const float* __restrict__ xs,  // (4096, 512)
             const float* __restrict__ C,   // (16, 512)
             float* __restrict__ ys)        // (4096, 16)
{
    const int step = blockIdx.x;
    const int lane = threadIdx.x & 63;
    const int wv   = threadIdx.x >> 6;  // 0..3
    const float* xrow = xs + step * NS;

#pragma unroll
    for (int oo = 0; oo < 4; ++oo) {
        const int o = (wv << 2) + oo;
        float p = 0.0f;
#pragma unroll
        for (int j = 0; j < 8; ++j)
            p += C[o * NS + lane + 64 * j] * xrow[lane + 64 * j];
#pragma unroll
        for (int m = 1; m < 64; m <<= 1) p += __shfl_xor(p, m, 64);
        if (lane == 0) ys[step * NO + o] = p;
    }
}

extern "C" void kernel_launch(void* const* d_in, const int* in_sizes, int n_in,
                              void* d_out, int out_size, void* d_ws, size_t ws_size,
                              hipStream_t stream) {
    const float* x0 = (const float*)d_in[0];
    const float* t  = (const float*)d_in[1];
    const float* uc = (const float*)d_in[2];
    const float* A  = (const float*)d_in[3];
    const float* B  = (const float*)d_in[4];
    const float* C  = (const float*)d_in[5];

    float* xs = (float*)d_out;            // 4096*512
    float* ys = xs + TT * NS;             // 4096*16

    flow_main<<<1, TPB, 0, stream>>>(x0, t, uc, A, B, xs);
    flow_ys<<<TT, 256, 0, stream>>>(xs, C, ys);
}

// Round 5
// 67672.284 us; speedup vs baseline: 6.3635x; 6.3635x over previous
//
#include <hip/hip_runtime.h>
#include <math.h>

#define NS 512          // states
#define NI 32           // inputs
#define NO 16           // outputs
#define TT 4096         // time points
#define NSTEP (TT - 1)  // 4095 integration steps
#define NIBLK 4         // integrator blocks: 4 CUs, fp32 A fits their RF (2MB)
#define NHEAT 64        // heater blocks (clock insurance, near-zero traffic)
#define TPB 512
#define FLAG_IDX 2048   // flag word index in XX (byte offset 16 KB)
#define MAGIC 0x511C0DEDu
#define HEAT_CAP 12000000ll  // 120 ms @ 100 MHz s_memrealtime

// Tagged dataflow: 4 slots x 512 x 8B = 16 KB in ws.
// word = (tag<<32) | fp32 bits. ws poison 0xAAAAAAAA never matches tag<=24570.
// 8B-word atomicity keeps value+tag consistent -> no fences.
// Block b owns rows [128b,128b+128); wave w owns 16 rows; lane l holds
// A[rbase+i][j*64+l] (16 rows x 8 cols = 128 VGPRs). Column-group j's FMAs
// fire as soon as word j*64+l has the stage tag for ALL lanes (__all), so
// compute overlaps the wait; post-detect path is reduce+publish only.

__global__ __launch_bounds__(TPB, 2)
void flow_main(const float* __restrict__ x0,
               const float* __restrict__ tt,
               const float* __restrict__ uc,   // (4, 4095, 32): d,c,b,a
               const float* __restrict__ A,    // (512, 512)
               const float* __restrict__ B,    // (512, 32)
               float* __restrict__ xs,         // (4096, 512)
               unsigned long long* __restrict__ XX)
{
    if (blockIdx.x >= NIBLK) {
        // ---- heater: long dependent-FMA bursts, rare flag/realtime check ----
        float z0 = (float)(blockIdx.x * 1024 + threadIdx.x) * 1e-6f + 0.1f;
        float z1 = z0 + 0.3f, z2 = z0 + 0.7f, z3 = z0 + 1.1f;
        const unsigned long long* flag = XX + FLAG_IDX;
        const long long t0 = (long long)__builtin_amdgcn_s_memrealtime();
        for (;;) {
#pragma unroll 4
            for (int i = 0; i < 16384; ++i) {
                z0 = fmaf(z0, 0.9999999f, 1e-7f);
                z1 = fmaf(z1, 0.9999998f, 2e-7f);
                z2 = fmaf(z2, 0.9999997f, 3e-7f);
                z3 = fmaf(z3, 0.9999996f, 4e-7f);
            }
            if ((unsigned)__hip_atomic_load(flag, __ATOMIC_RELAXED,
                                            __HIP_MEMORY_SCOPE_AGENT) == MAGIC)
                break;
            if ((long long)__builtin_amdgcn_s_memrealtime() - t0 > HEAT_CAP)
                break;
        }
        if (z0 + z1 + z2 + z3 == 123.4567f)   // never true; keeps z* alive
            ((float*)XX)[2 * FLAG_IDX + 64] = z0;
        return;
    }

    // ---- integrator ----
    const int tid = threadIdx.x;
    const int l   = tid & 63;
    const int w   = tid >> 6;                       // wave 0..7
    // fold levels at lane bits 5,4,3,2 -> row bit k comes from lane bit (5-k)
    const int rloc = ((l >> 5) & 1) | (((l >> 4) & 1) << 1)
                   | (((l >> 3) & 1) << 2) | (((l >> 2) & 1) << 3);
    const int rbase = blockIdx.x * 128 + w * 16;
    const int r     = rbase + rloc;                 // my quad's row (l&3 share)
    const int ch0   = (l & 3) * 8;                  // my 8 B/uc channels

    const float dt = tt[1] - tt[0];

    // A tile in registers: a[i][j] = A[rbase+i][j*64+l]
    float a[16][8];
#pragma unroll
    for (int i = 0; i < 16; ++i)
#pragma unroll
        for (int j = 0; j < 8; ++j)
            a[i][j] = A[(rbase + i) * NS + j * 64 + l];

    // my row's 8 B-channels
    float B8[8];
    {
        const float4 b0 = *(const float4*)&B[r * NI + ch0];
        const float4 b1 = *(const float4*)&B[r * NI + ch0 + 4];
        B8[0] = b0.x; B8[1] = b0.y; B8[2] = b0.z; B8[3] = b0.w;
        B8[4] = b1.x; B8[5] = b1.y; B8[6] = b1.z; B8[7] = b1.w;
    }

    float x = x0[r];                  // my row's state (quad-replicated)
    float xv0[8];                     // stage-0 input vector
#pragma unroll
    for (int j = 0; j < 8; ++j) xv0[j] = x0[j * 64 + l];
    if ((l & 3) == 0) xs[r] = x;

    const float SOFF[6] = {0.0f, 0.2f * dt, 0.3f * dt, 0.8f * dt,
                           (8.0f / 9.0f) * dt, dt};
    float k[6];

    for (int n = 0; n < NSTEP; ++n) {
        // Bu cubic coeffs for my row: pq = dot(B[r,:], uc_q[n,:]) (quad coop)
        const float* un = uc + n * NI + ch0;
        float pq[4];
#pragma unroll
        for (int qq = 0; qq < 4; ++qq) {
            const float4 v0 = *(const float4*)(un + qq * (NSTEP * NI));
            const float4 v1 = *(const float4*)(un + qq * (NSTEP * NI) + 4);
            float s0 = B8[0]*v0.x + B8[1]*v0.y + B8[2]*v0.z + B8[3]*v0.w
                     + B8[4]*v1.x + B8[5]*v1.y + B8[6]*v1.z + B8[7]*v1.w;
            s0 += __shfl_xor(s0, 1, 64);
            s0 += __shfl_xor(s0, 2, 64);
            pq[qq] = s0;
        }
        const float pd = pq[0], pc = pq[1], pb = pq[2], pa = pq[3];

#pragma unroll
        for (int s = 0; s < 6; ++s) {
            const int gs = n * 6 + s;

            float sc[16];
#pragma unroll
            for (int i = 0; i < 16; ++i) sc[i] = 0.0f;

            if (gs == 0) {
#pragma unroll
                for (int j = 0; j < 8; ++j)
#pragma unroll
                    for (int i = 0; i < 16; ++i)
                        sc[i] = fmaf(a[i][j], xv0[j], sc[i]);
            } else {
                // dataflow poll: chunk j's FMAs fire when its word is tagged
                unsigned long long* p = XX + ((unsigned)gs & 3u) * NS + l;
                unsigned done = 0;
                while (done != 0xFFu) {
                    unsigned long long v[8];
#pragma unroll
                    for (int j = 0; j < 8; ++j)
                        if (!(done & (1u << j)))
                            v[j] = __hip_atomic_load(p + 64 * j, __ATOMIC_RELAXED,
                                                     __HIP_MEMORY_SCOPE_AGENT);
#pragma unroll
                    for (int j = 0; j < 8; ++j) {
                        if (!(done & (1u << j))) {
                            if (__all((unsigned)(v[j] >> 32) == (unsigned)gs)) {
                                const float xvj = __uint_as_float((unsigned)v[j]);
#pragma unroll
                                for (int i = 0; i < 16; ++i)
                                    sc[i] = fmaf(a[i][j], xvj, sc[i]);
                                done |= (1u << j);
                            }
                        }
                    }
                }
            }

            // pack-butterfly: 16 row-sums over 64 lanes (4 fold levels + 2 adds)
            float t8[8];
#pragma unroll
            for (int i = 0; i < 8; ++i) {
                const float send = (l & 32) ? sc[2*i] : sc[2*i+1];
                const float keep = (l & 32) ? sc[2*i+1] : sc[2*i];
                t8[i] = keep + __shfl_xor(send, 32, 64);
            }
            float t4[4];
#pragma unroll
            for (int i = 0; i < 4; ++i) {
                const float send = (l & 16) ? t8[2*i] : t8[2*i+1];
                const float keep = (l & 16) ? t8[2*i+1] : t8[2*i];
                t4[i] = keep + __shfl_xor(send, 16, 64);
            }
            float t2[2];
#pragma unroll
            for (int i = 0; i < 2; ++i) {
                const float send = (l & 8) ? t4[2*i] : t4[2*i+1];
                const float keep = (l & 8) ? t4[2*i+1] : t4[2*i];
                t2[i] = keep + __shfl_xor(send, 8, 64);
            }
            float t1;
            {
                const float send = (l & 4) ? t2[0] : t2[1];
                const float keep = (l & 4) ? t2[1] : t2[0];
                t1 = keep + __shfl_xor(send, 4, 64);
                t1 += __shfl_xor(t1, 2, 64);
                t1 += __shfl_xor(t1, 1, 64);
            }

            const float sv = SOFF[s];
            const float bu = pa + sv * (pb + sv * (pc + sv * pd));
            const float e  = __expf(2.0f * t1);
            k[s] = (1.0f - 2.0f / (e + 1.0f)) + bu;

            float nxt;
            if (s == 0) {
                nxt = x + dt * (0.2f * k[0]);
            } else if (s == 1) {
                nxt = x + dt * ((3.0f / 40.0f) * k[0] + (9.0f / 40.0f) * k[1]);
            } else if (s == 2) {
                nxt = x + dt * ((44.0f / 45.0f) * k[0] + (-56.0f / 15.0f) * k[1] +
                                (32.0f / 9.0f) * k[2]);
            } else if (s == 3) {
                nxt = x + dt * ((19372.0f / 6561.0f) * k[0] + (-25360.0f / 2187.0f) * k[1] +
                                (64448.0f / 6561.0f) * k[2] + (-212.0f / 729.0f) * k[3]);
            } else if (s == 4) {
                nxt = x + dt * ((9017.0f / 3168.0f) * k[0] + (-355.0f / 33.0f) * k[1] +
                                (46732.0f / 5247.0f) * k[2] + (49.0f / 176.0f) * k[3] +
                                (-5103.0f / 18656.0f) * k[4]);
            } else {
                nxt = x + dt * ((35.0f / 384.0f) * k[0] + (500.0f / 1113.0f) * k[2] +
                                (125.0f / 192.0f) * k[3] + (-2187.0f / 6784.0f) * k[4] +
                                (11.0f / 84.0f) * k[5]);
                x = nxt;
                if ((l & 3) == 0) xs[(n + 1) * NS + r] = nxt;
            }

            const unsigned tag1 = (unsigned)(gs + 1);
            if ((l & 3) == 0) {
                const unsigned long long pv =
                    ((unsigned long long)tag1 << 32) |
                    (unsigned long long)__float_as_uint(nxt);
                __hip_atomic_store(&XX[(tag1 & 3u) * NS + r], pv,
                                   __ATOMIC_RELAXED, __HIP_MEMORY_SCOPE_AGENT);
            }
        }
    }

    // release the heaters
    if (tid == 0)
        __hip_atomic_store(XX + FLAG_IDX, (unsigned long long)MAGIC,
                           __ATOMIC_RELAXED, __HIP_MEMORY_SCOPE_AGENT);
}

__global__ __launch_bounds__(256, 1)
void flow_ys(const float* __restrict__ xs,  // (4096, 512)
             const float* __restrict__ C,   // (16, 512)
             float* __restrict__ ys)        // (4096, 16)
{
    const int step = blockIdx.x;
    const int lane = threadIdx.x & 63;
    const int wv   = threadIdx.x >> 6;  // 0..3
    const float* xrow = xs + step * NS;

#pragma unroll
    for (int oo = 0; oo < 4; ++oo) {
        const int o = (wv << 2) + oo;
        float p = 0.0f;
#pragma unroll
        for (int j = 0; j < 8; ++j)
            p += C[o * NS + lane + 64 * j] * xrow[lane + 64 * j];
#pragma unroll
        for (int m = 1; m < 64; m <<= 1) p += __shfl_xor(p, m, 64);
        if (lane == 0) ys[step * NO + o] = p;
    }
}

extern "C" void kernel_launch(void* const* d_in, const int* in_sizes, int n_in,
                              void* d_out, int out_size, void* d_ws, size_t ws_size,
                              hipStream_t stream) {
    const float* x0 = (const float*)d_in[0];
    const float* t  = (const float*)d_in[1];
    const float* uc = (const float*)d_in[2];
    const float* A  = (const float*)d_in[3];
    const float* B  = (const float*)d_in[4];
    const float* C  = (const float*)d_in[5];

    float* xs = (float*)d_out;            // 4096*512
    float* ys = xs + TT * NS;             // 4096*16
    unsigned long long* XX = (unsigned long long*)d_ws;  // 16 KB tags + flag

    flow_main<<<NIBLK + NHEAT, TPB, 0, stream>>>(x0, t, uc, A, B, xs, XX);
    flow_ys<<<TT, 256, 0, stream>>>(xs, C, ys);
}

// Round 8
// 66110.303 us; speedup vs baseline: 6.5138x; 1.0236x over previous
//
#include <hip/hip_runtime.h>
#include <math.h>

#define NS 512          // states
#define NI 32           // inputs
#define NO 16           // outputs
#define TT 4096         // time points
#define NSTEP (TT - 1)  // 4095 integration steps
#define TPB 512
#define NBLK_TOT 64     // launched blocks; 4 co-XCD blocks win the election
#define GK 4            // group size (4 CUs: 1 MB fp32 A fits their RFs)

// workspace layout (8B words), everything < 10.3 KB (proven-safe ws range):
//   0..1023        tag region, 2 slots x 512  (2-slot proof: publishing g+1
//                  requires the wave consumed ALL of stage g, and stage g's
//                  publish required all waves consumed g-1 -> slot reuse safe)
//   1024 + x*16    per-XCD claim counters (128B apart)
//   1200           winner word (xcc of winning XCD)
//   1216 + sb*16   hello words for the refresh handshake
//   1280           decision word: 1 = FAST (sc0/L2), 2 = SLOW (agent scope)
#define W_CNT   1024
#define W_WIN   1200
#define W_HELLO 1216
#define W_DEC   1280
#define POISON64 0xAAAAAAAAAAAAAAAAull
#define H1V 0x1111000011110001ull
#define H2V 0x2222000022220002ull
#define CAP_ELECT  10000000ll    // 0.1 s  @ 100 MHz s_memrealtime
#define CAP_HAND    1000000ll    // 10 ms
#define CAP_DEC    50000000ll    // 0.5 s
#define CAP_POLL  200000000ll    // 2 s (true-failure diagnostic, never perf)

// word = (tag<<32)|fp32 bits. Aligned 8B access is one transaction -> value+
// tag consistent, no fences. FAST mode: sc0 (SE-scope) loads/stores bypass the
// per-CU L1 and are served by the XCD-shared L2 (~200 cy). SLOW mode: agent-
// scope atomics via the device coherence point (~6500 cy, measured R5 floor).

__device__ __forceinline__ long long rt() {
    return (long long)__builtin_amdgcn_s_memrealtime();
}

__device__ __forceinline__ unsigned long long ld_sc0(const unsigned long long* p) {
    unsigned long long v;
    asm volatile("global_load_dwordx2 %0, %1, off sc0\n\ts_waitcnt vmcnt(0)"
                 : "=&v"(v) : "v"(p) : "memory");
    return v;
}

__device__ __forceinline__ void st_sc0(unsigned long long* p, unsigned long long v) {
    asm volatile("global_store_dwordx2 %0, %1, off sc0" :: "v"(p), "v"(v) : "memory");
}

__device__ __forceinline__ unsigned long long poll8(
    const unsigned long long* p,
    unsigned long long& v1, unsigned long long& v2, unsigned long long& v3,
    unsigned long long& v4, unsigned long long& v5, unsigned long long& v6,
    unsigned long long& v7)
{
    unsigned long long v0;
    asm volatile(
        "global_load_dwordx2 %0, %8, off sc0\n\t"
        "global_load_dwordx2 %1, %8, off offset:512 sc0\n\t"
        "global_load_dwordx2 %2, %8, off offset:1024 sc0\n\t"
        "global_load_dwordx2 %3, %8, off offset:1536 sc0\n\t"
        "global_load_dwordx2 %4, %8, off offset:2048 sc0\n\t"
        "global_load_dwordx2 %5, %8, off offset:2560 sc0\n\t"
        "global_load_dwordx2 %6, %8, off offset:3072 sc0\n\t"
        "global_load_dwordx2 %7, %8, off offset:3584 sc0\n\t"
        "s_waitcnt vmcnt(0)"
        : "=&v"(v0), "=&v"(v1), "=&v"(v2), "=&v"(v3),
          "=&v"(v4), "=&v"(v5), "=&v"(v6), "=&v"(v7)
        : "v"(p)
        : "memory");
    return v0;
}

__global__ __launch_bounds__(TPB, 2)
void flow_main(const float* __restrict__ x0,
               const float* __restrict__ tt,
               const float* __restrict__ uc,   // (4, 4095, 32): d,c,b,a
               const float* __restrict__ A,    // (512, 512)
               const float* __restrict__ B,    // (512, 32)
               float* __restrict__ xs,         // (4096, 512)
               unsigned long long* __restrict__ XX)
{
    const int tid = threadIdx.x;
    __shared__ int s_sb, s_mode;   // mode: 0=exit, 1=FAST(sc0), 2=SLOW(agent)

    if (tid == 0) {
        unsigned xcc;
        asm volatile("s_getreg_b32 %0, hwreg(HW_REG_XCC_ID)" : "=s"(xcc));
        xcc &= 7u;

        const unsigned long long old = __hip_atomic_fetch_add(
            &XX[W_CNT + (int)xcc * 16], 1ull,
            __ATOMIC_RELAXED, __HIP_MEMORY_SCOPE_AGENT);
        const int slot = (int)(unsigned)(old - POISON64);
        if (slot == GK - 1) {
            unsigned long long exp = POISON64;
            __hip_atomic_compare_exchange_strong(
                &XX[W_WIN], &exp, (unsigned long long)xcc,
                __ATOMIC_RELAXED, __ATOMIC_RELAXED, __HIP_MEMORY_SCOPE_AGENT);
        }
        long long t0 = rt();
        unsigned long long wv;
        for (;;) {
            wv = __hip_atomic_load(&XX[W_WIN], __ATOMIC_RELAXED,
                                   __HIP_MEMORY_SCOPE_AGENT);
            if (wv != POISON64) break;
            if (rt() - t0 > CAP_ELECT) break;
        }

        int mode = 0, sb = slot;
        if (wv == POISON64) {
            // should be unreachable (64 blocks -> some XCD has >=4); failsafe
            sb = blockIdx.x;
            mode = (blockIdx.x < GK) ? 2 : 0;
        } else if ((unsigned long long)xcc == wv && slot < GK) {
            // ---- two-phase refresh handshake over the sc0 path ----
            unsigned long long* hme = &XX[W_HELLO + slot * 16];
            st_sc0(hme, H1V);
            if (slot == 0) {
                bool ok = true;
                long long th = rt();
                for (int i = 1; i < GK && ok; ++i)       // phase 1: visibility
                    for (;;) {
                        const unsigned long long h = ld_sc0(&XX[W_HELLO + i * 16]);
                        if (h == H1V || h == H2V) break;
                        if (rt() - th > CAP_HAND) { ok = false; break; }
                    }
                st_sc0(hme, H2V);                        // "go": same word, new value
                th = rt();
                for (int i = 1; i < GK && ok; ++i)       // phase 2: refresh
                    for (;;) {
                        const unsigned long long h = ld_sc0(&XX[W_HELLO + i * 16]);
                        if (h == H2V) break;
                        if (rt() - th > CAP_HAND) { ok = false; break; }
                    }
                __hip_atomic_store(&XX[W_DEC], ok ? 1ull : 2ull,
                                   __ATOMIC_RELAXED, __HIP_MEMORY_SCOPE_AGENT);
                mode = ok ? 1 : 2;
            } else {
                long long th = rt();
                for (;;) {                               // my refresh test: H1->H2
                    const unsigned long long h = ld_sc0(&XX[W_HELLO + 0]);
                    if (h == H2V) break;
                    if (rt() - th > CAP_HAND) break;
                }
                st_sc0(hme, H2V);
                th = rt();
                unsigned long long dv;
                for (;;) {
                    dv = __hip_atomic_load(&XX[W_DEC], __ATOMIC_RELAXED,
                                           __HIP_MEMORY_SCOPE_AGENT);
                    if (dv != POISON64) break;
                    if (rt() - th > CAP_DEC) { dv = 2ull; break; }
                }
                mode = (dv == 1ull) ? 1 : 2;
            }
        }
        s_sb = sb; s_mode = mode;
    }
    __syncthreads();
    const int mode = s_mode;
    const int sb   = s_sb;
    if (mode == 0) return;
    const bool fast = (mode == 1);

    // ---- integrator (R5 register layout) ----
    const int l = tid & 63;
    const int w = tid >> 6;                         // wave 0..7
    const int rloc = ((l >> 5) & 1) | (((l >> 4) & 1) << 1)
                   | (((l >> 3) & 1) << 2) | (((l >> 2) & 1) << 3);
    const int rbase = sb * 128 + w * 16;
    const int r     = rbase + rloc;                 // my quad's row
    const int ch0   = (l & 3) * 8;                  // my 8 B/uc channels

    const float dt = tt[1] - tt[0];

    float a[16][8];                                 // A[rbase+i][j*64+l]
#pragma unroll
    for (int i = 0; i < 16; ++i)
#pragma unroll
        for (int j = 0; j < 8; ++j)
            a[i][j] = A[(rbase + i) * NS + j * 64 + l];

    float B8[8];
    {
        const float4 b0 = *(const float4*)&B[r * NI + ch0];
        const float4 b1 = *(const float4*)&B[r * NI + ch0 + 4];
        B8[0] = b0.x; B8[1] = b0.y; B8[2] = b0.z; B8[3] = b0.w;
        B8[4] = b1.x; B8[5] = b1.y; B8[6] = b1.z; B8[7] = b1.w;
    }

    float x = x0[r];
    float xv[8];
#pragma unroll
    for (int j = 0; j < 8; ++j) xv[j] = x0[j * 64 + l];
    if ((l & 3) == 0) xs[r] = x;

    const float SOFF[6] = {0.0f, 0.2f * dt, 0.3f * dt, 0.8f * dt,
                           (8.0f / 9.0f) * dt, dt};
    float k[6];
    const long long tstart = rt();

    for (int n = 0; n < NSTEP; ++n) {
        const float* un = uc + n * NI + ch0;
        float pq[4];
#pragma unroll
        for (int qq = 0; qq < 4; ++qq) {
            const float4 v0 = *(const float4*)(un + qq * (NSTEP * NI));
            const float4 v1 = *(const float4*)(un + qq * (NSTEP * NI) + 4);
            float s0 = B8[0]*v0.x + B8[1]*v0.y + B8[2]*v0.z + B8[3]*v0.w
                     + B8[4]*v1.x + B8[5]*v1.y + B8[6]*v1.z + B8[7]*v1.w;
            s0 += __shfl_xor(s0, 1, 64);
            s0 += __shfl_xor(s0, 2, 64);
            pq[qq] = s0;
        }
        const float pd = pq[0], pc = pq[1], pb = pq[2], pa = pq[3];

#pragma unroll
        for (int s = 0; s < 6; ++s) {
            const int gs = n * 6 + s;

            float sc[16];
#pragma unroll
            for (int i = 0; i < 16; ++i) sc[i] = 0.0f;

            if (gs == 0) {
#pragma unroll
                for (int j = 0; j < 8; ++j)
#pragma unroll
                    for (int i = 0; i < 16; ++i)
                        sc[i] = fmaf(a[i][j], xv[j], sc[i]);
            } else if (fast) {
                // FAST: batched sc0 sweep (one L2 round trip for all 8 words)
                const unsigned long long* p = XX + ((unsigned)gs & 1u) * NS + l;
                unsigned sweep = 0;
                for (;;) {
                    unsigned long long v1,v2,v3,v4,v5,v6,v7;
                    const unsigned long long v0 = poll8(p, v1,v2,v3,v4,v5,v6,v7);
                    const unsigned g = (unsigned)gs;
                    const bool ok = ((unsigned)(v0 >> 32) == g) &
                                    ((unsigned)(v1 >> 32) == g) &
                                    ((unsigned)(v2 >> 32) == g) &
                                    ((unsigned)(v3 >> 32) == g) &
                                    ((unsigned)(v4 >> 32) == g) &
                                    ((unsigned)(v5 >> 32) == g) &
                                    ((unsigned)(v6 >> 32) == g) &
                                    ((unsigned)(v7 >> 32) == g);
                    if (__all(ok)) {
                        xv[0] = __uint_as_float((unsigned)v0);
                        xv[1] = __uint_as_float((unsigned)v1);
                        xv[2] = __uint_as_float((unsigned)v2);
                        xv[3] = __uint_as_float((unsigned)v3);
                        xv[4] = __uint_as_float((unsigned)v4);
                        xv[5] = __uint_as_float((unsigned)v5);
                        xv[6] = __uint_as_float((unsigned)v6);
                        xv[7] = __uint_as_float((unsigned)v7);
                        break;
                    }
                    if (((++sweep) & 0x3FFu) == 0 && rt() - tstart > CAP_POLL)
                        return;
                }
#pragma unroll
                for (int j = 0; j < 8; ++j)
#pragma unroll
                    for (int i = 0; i < 16; ++i)
                        sc[i] = fmaf(a[i][j], xv[j], sc[i]);
            } else {
                // SLOW: proven R5 chunked agent-scope dataflow poll
                unsigned long long* p =
                    (unsigned long long*)XX + ((unsigned)gs & 1u) * NS + l;
                unsigned done = 0, sweep = 0;
                while (done != 0xFFu) {
                    unsigned long long v[8];
#pragma unroll
                    for (int j = 0; j < 8; ++j)
                        if (!(done & (1u << j)))
                            v[j] = __hip_atomic_load(p + 64 * j, __ATOMIC_RELAXED,
                                                     __HIP_MEMORY_SCOPE_AGENT);
#pragma unroll
                    for (int j = 0; j < 8; ++j) {
                        if (!(done & (1u << j))) {
                            if (__all((unsigned)(v[j] >> 32) == (unsigned)gs)) {
                                const float xvj = __uint_as_float((unsigned)v[j]);
#pragma unroll
                                for (int i = 0; i < 16; ++i)
                                    sc[i] = fmaf(a[i][j], xvj, sc[i]);
                                done |= (1u << j);
                            }
                        }
                    }
                    if (((++sweep) & 0xFFFu) == 0 && rt() - tstart > CAP_POLL)
                        return;
                }
            }

            // pack-butterfly: 16 row sums over 64 lanes
            float t8[8];
#pragma unroll
            for (int i = 0; i < 8; ++i) {
                const float send = (l & 32) ? sc[2*i] : sc[2*i+1];
                const float keep = (l & 32) ? sc[2*i+1] : sc[2*i];
                t8[i] = keep + __shfl_xor(send, 32, 64);
            }
            float t4[4];
#pragma unroll
            for (int i = 0; i < 4; ++i) {
                const float send = (l & 16) ? t8[2*i] : t8[2*i+1];
                const float keep = (l & 16) ? t8[2*i+1] : t8[2*i];
                t4[i] = keep + __shfl_xor(send, 16, 64);
            }
            float t2[2];
#pragma unroll
            for (int i = 0; i < 2; ++i) {
                const float send = (l & 8) ? t4[2*i] : t4[2*i+1];
                const float keep = (l & 8) ? t4[2*i+1] : t4[2*i];
                t2[i] = keep + __shfl_xor(send, 8, 64);
            }
            float t1;
            {
                const float send = (l & 4) ? t2[0] : t2[1];
                const float keep = (l & 4) ? t2[1] : t2[0];
                t1 = keep + __shfl_xor(send, 4, 64);
                t1 += __shfl_xor(t1, 2, 64);
                t1 += __shfl_xor(t1, 1, 64);
            }

            const float sv = SOFF[s];
            const float bu = pa + sv * (pb + sv * (pc + sv * pd));
            const float e  = __expf(2.0f * t1);
            k[s] = (1.0f - 2.0f / (e + 1.0f)) + bu;

            float nxt;
            if (s == 0) {
                nxt = x + dt * (0.2f * k[0]);
            } else if (s == 1) {
                nxt = x + dt * ((3.0f / 40.0f) * k[0] + (9.0f / 40.0f) * k[1]);
            } else if (s == 2) {
                nxt = x + dt * ((44.0f / 45.0f) * k[0] + (-56.0f / 15.0f) * k[1] +
                                (32.0f / 9.0f) * k[2]);
            } else if (s == 3) {
                nxt = x + dt * ((19372.0f / 6561.0f) * k[0] + (-25360.0f / 2187.0f) * k[1] +
                                (64448.0f / 6561.0f) * k[2] + (-212.0f / 729.0f) * k[3]);
            } else if (s == 4) {
                nxt = x + dt * ((9017.0f / 3168.0f) * k[0] + (-355.0f / 33.0f) * k[1] +
                                (46732.0f / 5247.0f) * k[2] + (49.0f / 176.0f) * k[3] +
                                (-5103.0f / 18656.0f) * k[4]);
            } else {
                nxt = x + dt * ((35.0f / 384.0f) * k[0] + (500.0f / 1113.0f) * k[2] +
                                (125.0f / 192.0f) * k[3] + (-2187.0f / 6784.0f) * k[4] +
                                (11.0f / 84.0f) * k[5]);
                x = nxt;
                if ((l & 3) == 0) xs[(n + 1) * NS + r] = nxt;
            }

            if ((l & 3) == 0) {
                const unsigned tag1 = (unsigned)(gs + 1);
                const unsigned long long pv =
                    ((unsigned long long)tag1 << 32) |
                    (unsigned long long)__float_as_uint(nxt);
                unsigned long long* dst = XX + (tag1 & 1u) * NS + r;
                if (fast) st_sc0(dst, pv);
                else __hip_atomic_store(dst, pv, __ATOMIC_RELAXED,
                                        __HIP_MEMORY_SCOPE_AGENT);
            }
        }
    }
}

__global__ __launch_bounds__(256, 1)
void flow_ys(const float* __restrict__ xs,  // (4096, 512)
             const float* __restrict__ C,   // (16, 512)
             float* __restrict__ ys)        // (4096, 16)
{
    const int step = blockIdx.x;
    const int lane = threadIdx.x & 63;
    const int wv   = threadIdx.x >> 6;  // 0..3
    const float* xrow = xs + step * NS;

#pragma unroll
    for (int oo = 0; oo < 4; ++oo) {
        const int o = (wv << 2) + oo;
        float p = 0.0f;
#pragma unroll
        for (int j = 0; j < 8; ++j)
            p += C[o * NS + lane + 64 * j] * xrow[lane + 64 * j];
#pragma unroll
        for (int m = 1; m < 64; m <<= 1) p += __shfl_xor(p, m, 64);
        if (lane == 0) ys[step * NO + o] = p;
    }
}

extern "C" void kernel_launch(void* const* d_in, const int* in_sizes, int n_in,
                              void* d_out, int out_size, void* d_ws, size_t ws_size,
                              hipStream_t stream) {
    const float* x0 = (const float*)d_in[0];
    const float* t  = (const float*)d_in[1];
    const float* uc = (const float*)d_in[2];
    const float* A  = (const float*)d_in[3];
    const float* B  = (const float*)d_in[4];
    const float* C  = (const float*)d_in[5];

    float* xs = (float*)d_out;            // 4096*512
    float* ys = xs + TT * NS;             // 4096*16
    unsigned long long* XX = (unsigned long long*)d_ws;  // < 10.3 KB used

    flow_main<<<NBLK_TOT, TPB, 0, stream>>>(x0, t, uc, A, B, xs, XX);
    flow_ys<<<TT, 256, 0, stream>>>(xs, C, ys);
}